// Round 7
// baseline (555.051 us; speedup 1.0000x reference)
//
#include <hip/hip_runtime.h>
#include <math.h>

constexpr int Bb = 64;
constexpr int Ss = 1024;
constexpr int Ff = 128;
constexpr int G2 = 256;   // 2F
constexpr int Kk = 64;
constexpr int NE = 1152;  // S + 64 (W^T cols for T2) + 64 pad

typedef __bf16 bfrag __attribute__((ext_vector_type(8)));
typedef float  facc  __attribute__((ext_vector_type(4)));
typedef short  s8v   __attribute__((ext_vector_type(8)));
typedef short  s4v   __attribute__((ext_vector_type(4)));

__device__ __forceinline__ short f2bfs(float f) {
  union { float f; unsigned u; } v; v.f = f;
  unsigned r = v.u + 0x7FFFu + ((v.u >> 16) & 1u);
  return (short)(r >> 16);
}
__device__ __forceinline__ float bf2fs(short s) {
  union { unsigned u; float f; } v; v.u = ((unsigned)(unsigned short)s) << 16;
  return v.f;
}
__device__ __forceinline__ facc mfma16(bfrag a, bfrag b, facc c) {
  return __builtin_amdgcn_mfma_f32_16x16x32_bf16(a, b, c, 0, 0, 0);
}
// async global->LDS, 16B per lane; LDS dest must be wave-uniform base + lane*16
__device__ __forceinline__ void gld16(const void* g, void* l) {
  __builtin_amdgcn_global_load_lds(
      (const __attribute__((address_space(1))) void*)g,
      (__attribute__((address_space(3))) void*)l, 16, 0, 0);
}

// ---------------- K0b: build AextT bf16 [3][NE][S]; row n: (A^T | W | 0) -----
__global__ void k_build_aextT(const float* __restrict__ Aa, const float* __restrict__ Av,
                              const float* __restrict__ Al, const float* __restrict__ Wa,
                              const float* __restrict__ Wv, const float* __restrict__ Wt,
                              short* __restrict__ aextT) {
  __shared__ float tile[64][65];
  int mod = blockIdx.z;
  const float* A = (mod == 0) ? Aa : (mod == 1) ? Av : Al;
  const float* W = (mod == 0) ? Wa : (mod == 1) ? Wv : Wt;
  short* dst = aextT + (size_t)mod * NE * Ss;
  int n0 = blockIdx.x * 64, t0 = blockIdx.y * 64;
  int tid = threadIdx.x;
  if (n0 < Ss) {
    {
      int fg = tid & 15, sb = tid >> 4;
#pragma unroll
      for (int i = 0; i < 4; ++i) {
        int ti = i * 16 + sb;
        float4 v = *(const float4*)(A + (size_t)(t0 + ti) * Ss + n0 + fg * 4);
        tile[ti][fg * 4 + 0] = v.x;
        tile[ti][fg * 4 + 1] = v.y;
        tile[ti][fg * 4 + 2] = v.z;
        tile[ti][fg * 4 + 3] = v.w;
      }
    }
    __syncthreads();
    {
      int tg = tid & 15, nb = tid >> 4;
#pragma unroll
      for (int i = 0; i < 4; ++i) {
        int nj = i * 16 + nb;
        s4v v;
        v[0] = f2bfs(tile[tg * 4 + 0][nj]);
        v[1] = f2bfs(tile[tg * 4 + 1][nj]);
        v[2] = f2bfs(tile[tg * 4 + 2][nj]);
        v[3] = f2bfs(tile[tg * 4 + 3][nj]);
        *(s4v*)(dst + (size_t)(n0 + nj) * Ss + t0 + tg * 4) = v;
      }
    }
  } else if (n0 < Ss + Kk) {
    for (int i = 0; i < 16; ++i) {
      int idx = i * 256 + tid;
      int j = idx >> 6, tt = idx & 63;
      dst[(size_t)(n0 + j) * Ss + t0 + tt] = f2bfs(W[(size_t)(n0 - Ss + j) * Ss + t0 + tt]);
    }
  } else {
    for (int i = 0; i < 16; ++i) {
      int idx = i * 256 + tid;
      int j = idx >> 6, tt = idx & 63;
      dst[(size_t)(n0 + j) * Ss + t0 + tt] = 0;
    }
  }
}

// ---------------- K0c: convert Wc, Wh; arrange AMLP W into reg frag layout ----
__global__ void k_build_w(const float* __restrict__ Wca, const float* __restrict__ Wcv,
                          const float* __restrict__ Wct, const float* __restrict__ Wha,
                          const float* __restrict__ Whv, const float* __restrict__ Wht,
                          const float* __restrict__ Wi, const float* __restrict__ Wq,
                          const float* __restrict__ Wvp,
                          short* __restrict__ wcb, short* __restrict__ whb,
                          short* __restrict__ wbar) {
  int idx = blockIdx.x * 256 + threadIdx.x;
  const int n1 = 3 * Kk * G2;                // 49152
  const int n2 = n1 + 3 * Ss * Kk;           // 245760
  if (idx < n1) {
    int mod = idx / (Kk * G2), r = idx - mod * (Kk * G2);
    const float* W = (mod == 0) ? Wca : (mod == 1) ? Wcv : Wct;
    wcb[idx] = f2bfs(W[r]);
  } else if (idx < n2) {
    int j = idx - n1;
    int mod = j / (Ss * Kk), r = j - mod * (Ss * Kk);
    const float* W = (mod == 0) ? Wha : (mod == 1) ? Whv : Wht;
    whb[j] = f2bfs(W[r]);
  } else {
    int j = idx - n2;                        // < 3*G2*Ff
    int mod = j / (G2 * Ff), r = j - mod * (G2 * Ff);
    int n = r >> 7, k = r & 127;             // W[n][k], n<256, k<128
    int t = n >> 4, nl = n & 15;             // n-tile, n-in-tile
    int c = k >> 5, q = (k >> 3) & 3, e = k & 7;  // k-chunk, quad, elem
    const float* W = (mod == 0) ? Wi : (mod == 1) ? Wq : Wvp;
    wbar[mod * G2 * Ff + (((t * 4 + c) * 64 + q * 16 + nl) * 8) + e] = f2bfs(W[r]);
  }
}

// ---------------- K1: AMLP f-GEMM + pooled p + sum(f^2) + fused x-transpose ---
// Transpose tail re-reads this block's 256x128 x tile (L1/L2-hot from the
// GEMM) and writes xT, eliminating the standalone k_transpose's 100MB cold
// HBM read. amlp mod {0,1,2}={txt,aud,vis} -> xT slot {2,0,1}.
__global__ void __launch_bounds__(256, 3) k_amlp(
    const float* __restrict__ txt, const float* __restrict__ aud, const float* __restrict__ vis,
    const float* __restrict__ bi, const float* __restrict__ bq, const float* __restrict__ bvp,
    const short* __restrict__ wbar,
    short* __restrict__ p1, short* __restrict__ p2, float* __restrict__ sumsq,
    short* __restrict__ xT) {
  int mod = blockIdx.y;
  const float* x    = (mod == 0) ? txt : (mod == 1) ? aud : vis;
  const float* bias = (mod == 0) ? bi  : (mod == 1) ? bq  : bvp;
  const short* wbm  = wbar + mod * G2 * Ff;
  short* pout = (mod == 0) ? p1 : (mod == 1) ? p2 : nullptr;

  __shared__ float wred[4];
  __shared__ float ttile[64][65];
  int tid = threadIdx.x, lane = tid & 63, wave = tid >> 6;
  int quad = lane >> 4, nl = lane & 15;

  bfrag wreg[4][4];
#pragma unroll
  for (int tt = 0; tt < 4; ++tt)
#pragma unroll
    for (int c = 0; c < 4; ++c)
      wreg[tt][c] = *(const bfrag*)(wbm + ((((wave * 4 + tt) * 4 + c) * 64 + lane) * 8));

  float bia[4];
#pragma unroll
  for (int tt = 0; tt < 4; ++tt) bia[tt] = bias[wave * 64 + tt * 16 + nl];

  const float* xblk = x + (size_t)(blockIdx.x * 256) * Ff;
  facc zero = {0.f, 0.f, 0.f, 0.f};
  float sq = 0.f;

  float4 buf[8];
  {
    const float* xrow = xblk + (size_t)nl * Ff;
#pragma unroll
    for (int c = 0; c < 4; ++c) {
      buf[c * 2]     = *(const float4*)(xrow + c * 32 + quad * 8);
      buf[c * 2 + 1] = *(const float4*)(xrow + c * 32 + quad * 8 + 4);
    }
  }

  for (int g = 0; g < 16; ++g) {
    bfrag af[4];
#pragma unroll
    for (int c = 0; c < 4; ++c) {
      float4 a0 = buf[c * 2], a1 = buf[c * 2 + 1];
      af[c][0] = (__bf16)a0.x; af[c][1] = (__bf16)a0.y;
      af[c][2] = (__bf16)a0.z; af[c][3] = (__bf16)a0.w;
      af[c][4] = (__bf16)a1.x; af[c][5] = (__bf16)a1.y;
      af[c][6] = (__bf16)a1.z; af[c][7] = (__bf16)a1.w;
    }
    if (g < 15) {
      const float* xrow = xblk + (size_t)((g + 1) * 16 + nl) * Ff;
#pragma unroll
      for (int c = 0; c < 4; ++c) {
        buf[c * 2]     = *(const float4*)(xrow + c * 32 + quad * 8);
        buf[c * 2 + 1] = *(const float4*)(xrow + c * 32 + quad * 8 + 4);
      }
    }
    facc acc[4];
#pragma unroll
    for (int tt = 0; tt < 4; ++tt) acc[tt] = zero;
#pragma unroll
    for (int c = 0; c < 4; ++c)
#pragma unroll
      for (int tt = 0; tt < 4; ++tt)
        acc[tt] = mfma16(af[c], wreg[tt][c], acc[tt]);

    int drow = blockIdx.x * 256 + g * 16 + quad * 4;
#pragma unroll
    for (int tt = 0; tt < 4; ++tt)
#pragma unroll
      for (int r = 0; r < 4; ++r) {
        float fv = acc[tt][r] + bia[tt];
        sq += fv * fv;
        if (pout) {
          float fo = fv + __shfl_xor(fv, 1, 64);       // pair-pool along n
          if ((lane & 1) == 0)
            pout[(size_t)(drow + r) * Ff + wave * 32 + tt * 8 + (nl >> 1)] = f2bfs(fo);
        }
      }
  }
  for (int off = 32; off > 0; off >>= 1) sq += __shfl_down(sq, off, 64);
  if (lane == 0) wred[wave] = sq;
  __syncthreads();
  if (tid == 0) atomicAdd(&sumsq[mod], wred[0] + wred[1] + wred[2] + wred[3]);

  // ---- fused transpose tail: 8 sub-tiles of 64s x 64f ----
  int slot = (mod == 0) ? 2 : (mod == 1) ? 0 : 1;
  int b = blockIdx.x >> 2, s0 = (blockIdx.x & 3) * 256;
  short* xdst = xT + ((size_t)slot * Bb + b) * Ff * Ss;
  for (int t = 0; t < 8; ++t) {
    int sc = (t >> 1) * 64, fc = (t & 1) * 64;
    __syncthreads();
    {
      int fg = tid & 15, sb = tid >> 4;
#pragma unroll
      for (int i = 0; i < 4; ++i) {
        int si = i * 16 + sb;
        float4 v = *(const float4*)(x + ((size_t)b * Ss + s0 + sc + si) * Ff + fc + fg * 4);
        ttile[si][fg * 4 + 0] = v.x;
        ttile[si][fg * 4 + 1] = v.y;
        ttile[si][fg * 4 + 2] = v.z;
        ttile[si][fg * 4 + 3] = v.w;
      }
    }
    __syncthreads();
    {
      int sg = tid & 15, fb = tid >> 4;
#pragma unroll
      for (int i = 0; i < 4; ++i) {
        int fi = i * 16 + fb;
        s4v v;
        v[0] = f2bfs(ttile[sg * 4 + 0][fi]);
        v[1] = f2bfs(ttile[sg * 4 + 1][fi]);
        v[2] = f2bfs(ttile[sg * 4 + 2][fi]);
        v[3] = f2bfs(ttile[sg * 4 + 3][fi]);
        *(s4v*)(xdst + (size_t)(fc + fi) * Ss + s0 + sc + sg * 4) = v;
      }
    }
  }
}

// ---------------- K2: column norms over s of z, vectorized s8v loads ----------
__global__ void k_colnorm(const short* __restrict__ p1, const short* __restrict__ p2,
                          const float* __restrict__ sumsq, float* __restrict__ colnsq) {
  __shared__ float part[16][128];
  float n1 = sqrtf(sumsq[0]), n2 = sqrtf(sumsq[1]), n3 = sqrtf(sumsq[2]);
  float w1 = n1 / (n1 + n2), w2 = n2 / (n1 + n2);
  float tc = 2.f * n3 * n3 / (n1 + n2 + n3);
  int b = blockIdx.x, s0 = blockIdx.y * 128;
  int tid = threadIdx.x, fi = (tid & 15) * 8, sl = tid >> 4;
  float a[8];
#pragma unroll
  for (int j = 0; j < 8; ++j) a[j] = 0.f;
  for (int st = 0; st < 8; ++st) {
    size_t off = ((size_t)b * Ss + s0 + st * 16 + sl) * Ff + fi;
    s8v v1 = *(const s8v*)(p1 + off);
    s8v v2 = *(const s8v*)(p2 + off);
#pragma unroll
    for (int j = 0; j < 8; ++j) {
      float z = w1 * bf2fs(v1[j]) + w2 * bf2fs(v2[j]) + tc;
      a[j] += z * z;
    }
  }
#pragma unroll
  for (int j = 0; j < 8; ++j) part[sl][fi + j] = a[j];
  __syncthreads();
  if (tid < 128) {
    float s = 0.f;
    for (int i = 0; i < 16; ++i) s += part[i][tid];
    atomicAdd(&colnsq[b * Ff + tid], s);
  }
}

// ---------------- K3: gT[b][f][s] = z * invcn, tiled transpose ----------------
__global__ void k_gnormT(const short* __restrict__ p1, const short* __restrict__ p2,
                         const float* __restrict__ sumsq, const float* __restrict__ colnsq,
                         short* __restrict__ gT) {
  __shared__ float tile[64][65];
  __shared__ float invcn[64];
  float n1 = sqrtf(sumsq[0]), n2 = sqrtf(sumsq[1]), n3 = sqrtf(sumsq[2]);
  float w1 = n1 / (n1 + n2), w2 = n2 / (n1 + n2);
  float tc = 2.f * n3 * n3 / (n1 + n2 + n3);
  int b = blockIdx.z, s0 = blockIdx.x * 64, f0 = blockIdx.y * 64;
  int tid = threadIdx.x;
  if (tid < 64)
    invcn[tid] = 1.f / fmaxf(sqrtf(colnsq[b * Ff + f0 + tid]), 1e-12f);
  __syncthreads();
  for (int i = 0; i < 16; ++i) {
    int idx = i * 256 + tid;
    int si = idx >> 6, fi = idx & 63;
    size_t off = ((size_t)b * Ss + s0 + si) * Ff + f0 + fi;
    float z = w1 * bf2fs(p1[off]) + w2 * bf2fs(p2[off]) + tc;
    tile[si][fi] = z * invcn[fi];
  }
  __syncthreads();
  short* dst = gT + (size_t)b * Ff * Ss;
  {
    int sg = tid & 15, fb = tid >> 4;
#pragma unroll
    for (int i = 0; i < 4; ++i) {
      int fi = i * 16 + fb;
      s4v v;
      v[0] = f2bfs(tile[sg * 4 + 0][fi]);
      v[1] = f2bfs(tile[sg * 4 + 1][fi]);
      v[2] = f2bfs(tile[sg * 4 + 2][fi]);
      v[3] = f2bfs(tile[sg * 4 + 3][fi]);
      *(s4v*)(dst + (size_t)(f0 + fi) * Ss + s0 + sg * 4) = v;
    }
  }
}

// ---------------- K4: M-GEMM (N=1152 incl. T2 cols), XOR-swizzled LDS --------
// Single-buffered 2-phase loop (proven best). XCD swizzle on M.
__global__ void __launch_bounds__(256) k_mgemm(const short* __restrict__ xT,
                                               const short* __restrict__ aextT,
                                               short* __restrict__ mxext) {
  int mod = blockIdx.z;
  const short* Ap = xT + (size_t)mod * Bb * Ff * Ss;
  const short* Bp = aextT + (size_t)mod * NE * Ss;
  short* Op = mxext + (size_t)mod * Bb * Ff * NE;
  int bx = blockIdx.x;
  int swzx = (bx & 7) * 8 + (bx >> 3);       // bijective on 64
  int M0 = swzx * 128, N0 = blockIdx.y * 128;
  __shared__ short As[128 * 64];   // 16KB
  __shared__ short Bs[128 * 64];   // 16KB
  int tid = threadIdx.x, lane = tid & 63, wave = tid >> 6;
  int quad = lane >> 4, nl = lane & 15;
  int wm = (wave >> 1) * 64, wn = (wave & 1) * 64;
  facc zero = {0.f, 0.f, 0.f, 0.f};
  facc acc[4][4];
  for (int i = 0; i < 4; ++i) for (int j = 0; j < 4; ++j) acc[i][j] = zero;
  for (int k0 = 0; k0 < Ss; k0 += 64) {
    __syncthreads();
#pragma unroll
    for (int i = 0; i < 4; ++i) {
      int idx = i * 256 + tid;
      int r = idx >> 3, cs = ((idx & 7) ^ (r & 7)) * 8;
      gld16(Ap + (size_t)(M0 + r) * Ss + k0 + cs, As + idx * 8);
      gld16(Bp + (size_t)(N0 + r) * Ss + k0 + cs, Bs + idx * 8);
    }
    __syncthreads();
#pragma unroll
    for (int kc = 0; kc < 2; ++kc) {
      bfrag a[4], bfr[4];
      for (int mt = 0; mt < 4; ++mt) {
        int row = wm + mt * 16 + nl;
        a[mt] = *(const bfrag*)(As + row * 64 + (((kc * 4 + quad) ^ (row & 7)) * 8));
      }
      for (int nt = 0; nt < 4; ++nt) {
        int row = wn + nt * 16 + nl;
        bfr[nt] = *(const bfrag*)(Bs + row * 64 + (((kc * 4 + quad) ^ (row & 7)) * 8));
      }
      for (int mt = 0; mt < 4; ++mt)
        for (int nt = 0; nt < 4; ++nt)
          acc[mt][nt] = mfma16(a[mt], bfr[nt], acc[mt][nt]);
    }
  }
  for (int mt = 0; mt < 4; ++mt)
    for (int nt = 0; nt < 4; ++nt)
      for (int r = 0; r < 4; ++r) {
        int row = M0 + wm + mt * 16 + quad * 4 + r;
        int col = N0 + wn + nt * 16 + nl;
        Op[(size_t)row * NE + col] = f2bfs(acc[mt][nt][r]);
      }
}

// ---------------- K5: fused C-GEMM + H-GEMM, mod-paired B sharing -------------
// grid (B, 2, 2): group 0 computes mods {0,1} (identical B = [aud|G], source
// bug) with ONE B-stage; group 1 computes mod 2 ([txt|G]). 256 blocks = 1/CU.
__global__ void __launch_bounds__(256) k_chgemm(const short* __restrict__ mxext,
                                                const short* __restrict__ xT,
                                                const short* __restrict__ gT,
                                                const short* __restrict__ wcb,
                                                short* __restrict__ h) {
  int b = blockIdx.x, grp = blockIdx.y, half = blockIdx.z;
  int r0 = half * 64;                        // this block's C-row offset
  int two = (grp == 0);                      // group 0 handles mods 0 and 1
  int mbase = two ? 0 : 2;
  const short* Ap0 = mxext + ((size_t)mbase * Bb + b) * Ff * NE;
  const short* Ap1 = mxext + ((size_t)(mbase + 1) * Bb + b) * Ff * NE;  // grp0 only
  const short* xTb = xT + (size_t)(two ? 0 : 2) * Bb * Ff * Ss + (size_t)b * Ff * Ss;
  const short* gTb = gT + (size_t)b * Ff * Ss;
  const short* Wp0 = wcb + (size_t)mbase * Kk * G2;
  const short* Wp1 = wcb + (size_t)(mbase + 1) * Kk * G2;
  short* Hp0 = h + ((size_t)mbase * Bb + b) * Ff * Kk;
  short* Hp1 = h + ((size_t)(mbase + 1) * Bb + b) * Ff * Kk;

  __shared__ short smem[2 * 64 * 280];       // 70KB; staging uses first 48KB
  short* As0 = smem;                         // [64][64]
  short* As1 = smem + 64 * 64;               // [64][64]
  short* Bs  = smem + 2 * 64 * 64;           // [256][64]
  // post-loop reuse: Cs0 [64][280], Cs1 [64][280]

  int tid = threadIdx.x, lane = tid & 63, wave = tid >> 6;
  int quad = lane >> 4, nl = lane & 15;
  int wn = wave * 64;                        // wave owns 64 cols, all 64 rows
  facc zero = {0.f, 0.f, 0.f, 0.f};
  facc acc[2][4][4];
  for (int m = 0; m < 2; ++m)
    for (int i = 0; i < 4; ++i)
      for (int j = 0; j < 4; ++j) acc[m][i][j] = zero;

  for (int k0 = 0; k0 < Ss; k0 += 64) {
    __syncthreads();
#pragma unroll
    for (int i = 0; i < 2; ++i) {            // A0: 64 rows
      int idx = i * 256 + tid;
      int r = idx >> 3, cs = ((idx & 7) ^ (r & 7)) * 8;
      gld16(Ap0 + (size_t)(r0 + r) * NE + k0 + cs, As0 + idx * 8);
    }
    if (two) {
#pragma unroll
      for (int i = 0; i < 2; ++i) {          // A1: 64 rows
        int idx = i * 256 + tid;
        int r = idx >> 3, cs = ((idx & 7) ^ (r & 7)) * 8;
        gld16(Ap1 + (size_t)(r0 + r) * NE + k0 + cs, As1 + idx * 8);
      }
    }
#pragma unroll
    for (int i = 0; i < 8; ++i) {            // B: 256 rows (128 x | 128 g)
      int idx = i * 256 + tid;
      int r = idx >> 3, cs = ((idx & 7) ^ (r & 7)) * 8;
      const short* src = (r < 128) ? (xTb + (size_t)r * Ss) : (gTb + (size_t)(r - 128) * Ss);
      gld16(src + k0 + cs, Bs + idx * 8);
    }
    __syncthreads();
#pragma unroll
    for (int kc = 0; kc < 2; ++kc) {
      bfrag a0[4], a1[4], bfr[4];
      for (int mt = 0; mt < 4; ++mt) {
        int row = mt * 16 + nl;
        int sw = (((kc * 4 + quad) ^ (row & 7)) * 8);
        a0[mt] = *(const bfrag*)(As0 + row * 64 + sw);
        if (two) a1[mt] = *(const bfrag*)(As1 + row * 64 + sw);
      }
      for (int nt = 0; nt < 4; ++nt) {
        int row = wn + nt * 16 + nl;
        bfr[nt] = *(const bfrag*)(Bs + row * 64 + (((kc * 4 + quad) ^ (row & 7)) * 8));
      }
      for (int mt = 0; mt < 4; ++mt)
        for (int nt = 0; nt < 4; ++nt)
          acc[0][mt][nt] = mfma16(a0[mt], bfr[nt], acc[0][mt][nt]);
      if (two)
        for (int mt = 0; mt < 4; ++mt)
          for (int nt = 0; nt < 4; ++nt)
            acc[1][mt][nt] = mfma16(a1[mt], bfr[nt], acc[1][mt][nt]);
    }
  }
  __syncthreads();                           // staging dead; reuse smem
  short* Cs0 = smem;                         // [64][280]
  short* Cs1 = smem + 64 * 280;              // [64][280]
  for (int mt = 0; mt < 4; ++mt)
    for (int nt = 0; nt < 4; ++nt)
      for (int r = 0; r < 4; ++r) {
        int row = mt * 16 + quad * 4 + r;    // local C row (0..63)
        int col = wn + nt * 16 + nl;
        Cs0[row * 280 + col] = f2bfs(tanhf(acc[0][mt][nt][r] * 0.0625f));
        if (two) Cs1[row * 280 + col] = f2bfs(tanhf(acc[1][mt][nt][r] * 0.0625f));
      }
  __syncthreads();
  // H phase: wave w handles local C rows [16w, 16w+16), per mod
  for (int m = 0; m < 2; ++m) {
    if (m == 1 && !two) break;
    const short* Cs = (m == 0) ? Cs0 : Cs1;
    const short* Wp = (m == 0) ? Wp0 : Wp1;
    const short* Ap = (m == 0) ? Ap0 : Ap1;
    short* Hp = (m == 0) ? Hp0 : Hp1;
    facc hacc[4];
    for (int nt = 0; nt < 4; ++nt) hacc[nt] = zero;
    for (int k0 = 0; k0 < G2; k0 += 32) {
      bfrag ca = *(const bfrag*)(Cs + (wave * 16 + nl) * 280 + k0 + quad * 8);
      for (int nt = 0; nt < 4; ++nt) {
        bfrag wb = *(const bfrag*)(Wp + (size_t)(nt * 16 + nl) * G2 + k0 + quad * 8);
        hacc[nt] = mfma16(ca, wb, hacc[nt]);
      }
    }
    for (int nt = 0; nt < 4; ++nt)
      for (int r = 0; r < 4; ++r) {
        int lrow = wave * 16 + quad * 4 + r;
        int col = nt * 16 + nl;
        float v = hacc[nt][r] + bf2fs(Ap[(size_t)(r0 + lrow) * NE + Ss + col]);  // + T2
        Hp[(size_t)(r0 + lrow) * Kk + col] = f2bfs(fmaxf(v, 0.f));
      }
  }
}

// ---------------- K7: out = Wh @ H^T + residual ------------------------------
__global__ void k_outgemm(const short* __restrict__ whb, const short* __restrict__ h,
                          const float* __restrict__ txt, const float* __restrict__ aud,
                          const float* __restrict__ vis, float* __restrict__ outp) {
  int s0 = blockIdx.x * 128, b = blockIdx.y, mod = blockIdx.z;
  const short* Wp = whb + (size_t)mod * Ss * Kk;
  const short* Hp = h + ((size_t)mod * Bb + b) * Ff * Kk;
  const float* xres = ((mod == 0) ? aud : (mod == 1) ? vis : txt) + (size_t)b * Ss * Ff;
  int slot = (mod == 0) ? 1 : (mod == 1) ? 2 : 0;   // output order (t, a, v)
  float* Op = outp + ((size_t)slot * Bb + b) * Ss * Ff;
  int tid = threadIdx.x, lane = tid & 63, wave = tid >> 6;
  int quad = lane >> 4, nl = lane & 15;
  int wm = (wave >> 1) * 64, wn = (wave & 1) * 64;
  facc zero = {0.f, 0.f, 0.f, 0.f};
  facc acc[4][4];
  for (int i = 0; i < 4; ++i) for (int j = 0; j < 4; ++j) acc[i][j] = zero;
  for (int k0 = 0; k0 < Kk; k0 += 32) {
    bfrag a[4], bfr[4];
    for (int mt = 0; mt < 4; ++mt)
      a[mt] = *(const bfrag*)(Wp + (size_t)(s0 + wm + mt * 16 + nl) * Kk + k0 + quad * 8);
    for (int nt = 0; nt < 4; ++nt)
      bfr[nt] = *(const bfrag*)(Hp + (size_t)(wn + nt * 16 + nl) * Kk + k0 + quad * 8);
    for (int mt = 0; mt < 4; ++mt)
      for (int nt = 0; nt < 4; ++nt)
        acc[mt][nt] = mfma16(a[mt], bfr[nt], acc[mt][nt]);
  }
  for (int mt = 0; mt < 4; ++mt)
    for (int nt = 0; nt < 4; ++nt)
      for (int r = 0; r < 4; ++r) {
        int srow = s0 + wm + mt * 16 + quad * 4 + r;
        int col = wn + nt * 16 + nl;
        size_t o = (size_t)srow * Ff + col;
        Op[o] = acc[mt][nt][r] + xres[o];
      }
}

extern "C" void kernel_launch(void* const* d_in, const int* in_sizes, int n_in,
                              void* d_out, int out_size, void* d_ws, size_t ws_size,
                              hipStream_t stream) {
  const float* txt = (const float*)d_in[0];
  const float* aud = (const float*)d_in[1];
  const float* vis = (const float*)d_in[2];
  const float* Wi  = (const float*)d_in[3];
  const float* bi  = (const float*)d_in[4];
  const float* Wq  = (const float*)d_in[5];
  const float* bq  = (const float*)d_in[6];
  const float* Wvp = (const float*)d_in[7];
  const float* bvp = (const float*)d_in[8];
  const float* Aa  = (const float*)d_in[9];
  const float* Av  = (const float*)d_in[10];
  const float* Al  = (const float*)d_in[11];
  const float* Wa  = (const float*)d_in[12];
  const float* Wv  = (const float*)d_in[13];
  const float* Wt  = (const float*)d_in[14];
  const float* Wca = (const float*)d_in[15];
  const float* Wcv = (const float*)d_in[16];
  const float* Wct = (const float*)d_in[17];
  const float* Wha = (const float*)d_in[18];
  const float* Whv = (const float*)d_in[19];
  const float* Wht = (const float*)d_in[20];

  char* w = (char*)d_ws;
  float* sumsq  = (float*)w;                    // 3 floats
  float* colnsq = (float*)(w + 256);            // B*F floats
  size_t off = 65536;
  short* xT    = (short*)(w + off); off += (size_t)3 * Bb * Ff * Ss * 2;   // 48MB
  short* aextT = (short*)(w + off); off += (size_t)3 * NE * Ss * 2;        // 6.75MB
  short* gT    = (short*)(w + off); off += (size_t)Bb * Ff * Ss * 2;       // 16MB
  short* mx    = (short*)(w + off);                                        // 54MB
  short* p1    = mx;                             // p1/p2 overlaid under mx:
  short* p2    = mx + (size_t)Bb * Ss * Ff;      // dead before k_mgemm writes
  off += (size_t)3 * Bb * Ff * NE * 2;
  short* h     = (short*)(w + off); off += (size_t)3 * Bb * Ff * Kk * 2;   // 3MB
  short* wcb   = (short*)(w + off); off += (size_t)3 * Kk * G2 * 2;
  short* whb   = (short*)(w + off); off += (size_t)3 * Ss * Kk * 2;
  short* wbar  = (short*)(w + off); off += (size_t)3 * G2 * Ff * 2;

  hipMemsetAsync(d_ws, 0, 65536, stream);   // zero sumsq + colnsq
  k_build_aextT<<<dim3(NE / 64, 16, 3), 256, 0, stream>>>(Aa, Av, Al, Wa, Wv, Wt, aextT);
  k_build_w<<<(3 * Kk * G2 + 3 * Ss * Kk + 3 * G2 * Ff) / 256, 256, 0, stream>>>(
      Wca, Wcv, Wct, Wha, Whv, Wht, Wi, Wq, Wvp, wcb, whb, wbar);
  k_amlp<<<dim3(Bb * Ss / 256, 3), 256, 0, stream>>>(txt, aud, vis, bi, bq, bvp,
                                                     wbar, p1, p2, sumsq, xT);
  k_colnorm<<<dim3(Bb, 8), 256, 0, stream>>>(p1, p2, sumsq, colnsq);
  k_gnormT<<<dim3(16, 2, Bb), 256, 0, stream>>>(p1, p2, sumsq, colnsq, gT);
  k_mgemm<<<dim3(Bb * Ff / 128, NE / 128, 3), 256, 0, stream>>>(xT, aextT, mx);
  k_chgemm<<<dim3(Bb, 2, 2), 256, 0, stream>>>(mx, xT, gT, wcb, h);
  k_outgemm<<<dim3(Ss / 128, Bb, 3), 256, 0, stream>>>(whb, h, txt, aud, vis, (float*)d_out);
}

// Round 8
// 430.015 us; speedup vs baseline: 1.2908x; 1.2908x over previous
//
#include <hip/hip_runtime.h>
#include <math.h>

constexpr int Bb = 64;
constexpr int Ss = 1024;
constexpr int Ff = 128;
constexpr int G2 = 256;   // 2F
constexpr int Kk = 64;
constexpr int NE = 1152;  // S + 64 (W^T cols for T2) + 64 pad

typedef __bf16 bfrag __attribute__((ext_vector_type(8)));
typedef float  facc  __attribute__((ext_vector_type(4)));
typedef short  s8v   __attribute__((ext_vector_type(8)));
typedef short  s4v   __attribute__((ext_vector_type(4)));

__device__ __forceinline__ short f2bfs(float f) {
  union { float f; unsigned u; } v; v.f = f;
  unsigned r = v.u + 0x7FFFu + ((v.u >> 16) & 1u);
  return (short)(r >> 16);
}
__device__ __forceinline__ float bf2fs(short s) {
  union { unsigned u; float f; } v; v.u = ((unsigned)(unsigned short)s) << 16;
  return v.f;
}
__device__ __forceinline__ facc mfma16(bfrag a, bfrag b, facc c) {
  return __builtin_amdgcn_mfma_f32_16x16x32_bf16(a, b, c, 0, 0, 0);
}
// async global->LDS, 16B per lane; LDS dest must be wave-uniform base + lane*16
__device__ __forceinline__ void gld16(const void* g, void* l) {
  __builtin_amdgcn_global_load_lds(
      (const __attribute__((address_space(1))) void*)g,
      (__attribute__((address_space(3))) void*)l, 16, 0, 0);
}

// ---------------- K0b: build AextT bf16 [3][NE][S]; row n: (A^T | W | 0) -----
__global__ void k_build_aextT(const float* __restrict__ Aa, const float* __restrict__ Av,
                              const float* __restrict__ Al, const float* __restrict__ Wa,
                              const float* __restrict__ Wv, const float* __restrict__ Wt,
                              short* __restrict__ aextT) {
  __shared__ float tile[64][65];
  int mod = blockIdx.z;
  const float* A = (mod == 0) ? Aa : (mod == 1) ? Av : Al;
  const float* W = (mod == 0) ? Wa : (mod == 1) ? Wv : Wt;
  short* dst = aextT + (size_t)mod * NE * Ss;
  int n0 = blockIdx.x * 64, t0 = blockIdx.y * 64;
  int tid = threadIdx.x;
  if (n0 < Ss) {
    {
      int fg = tid & 15, sb = tid >> 4;
#pragma unroll
      for (int i = 0; i < 4; ++i) {
        int ti = i * 16 + sb;
        float4 v = *(const float4*)(A + (size_t)(t0 + ti) * Ss + n0 + fg * 4);
        tile[ti][fg * 4 + 0] = v.x;
        tile[ti][fg * 4 + 1] = v.y;
        tile[ti][fg * 4 + 2] = v.z;
        tile[ti][fg * 4 + 3] = v.w;
      }
    }
    __syncthreads();
    {
      int tg = tid & 15, nb = tid >> 4;
#pragma unroll
      for (int i = 0; i < 4; ++i) {
        int nj = i * 16 + nb;
        s4v v;
        v[0] = f2bfs(tile[tg * 4 + 0][nj]);
        v[1] = f2bfs(tile[tg * 4 + 1][nj]);
        v[2] = f2bfs(tile[tg * 4 + 2][nj]);
        v[3] = f2bfs(tile[tg * 4 + 3][nj]);
        *(s4v*)(dst + (size_t)(n0 + nj) * Ss + t0 + tg * 4) = v;
      }
    }
  } else if (n0 < Ss + Kk) {
    for (int i = 0; i < 16; ++i) {
      int idx = i * 256 + tid;
      int j = idx >> 6, tt = idx & 63;
      dst[(size_t)(n0 + j) * Ss + t0 + tt] = f2bfs(W[(size_t)(n0 - Ss + j) * Ss + t0 + tt]);
    }
  } else {
    for (int i = 0; i < 16; ++i) {
      int idx = i * 256 + tid;
      int j = idx >> 6, tt = idx & 63;
      dst[(size_t)(n0 + j) * Ss + t0 + tt] = 0;
    }
  }
}

// ---------------- K0c: convert Wc, Wh; arrange AMLP W into reg frag layout ----
__global__ void k_build_w(const float* __restrict__ Wca, const float* __restrict__ Wcv,
                          const float* __restrict__ Wct, const float* __restrict__ Wha,
                          const float* __restrict__ Whv, const float* __restrict__ Wht,
                          const float* __restrict__ Wi, const float* __restrict__ Wq,
                          const float* __restrict__ Wvp,
                          short* __restrict__ wcb, short* __restrict__ whb,
                          short* __restrict__ wbar) {
  int idx = blockIdx.x * 256 + threadIdx.x;
  const int n1 = 3 * Kk * G2;                // 49152
  const int n2 = n1 + 3 * Ss * Kk;           // 245760
  if (idx < n1) {
    int mod = idx / (Kk * G2), r = idx - mod * (Kk * G2);
    const float* W = (mod == 0) ? Wca : (mod == 1) ? Wcv : Wct;
    wcb[idx] = f2bfs(W[r]);
  } else if (idx < n2) {
    int j = idx - n1;
    int mod = j / (Ss * Kk), r = j - mod * (Ss * Kk);
    const float* W = (mod == 0) ? Wha : (mod == 1) ? Whv : Wht;
    whb[j] = f2bfs(W[r]);
  } else {
    int j = idx - n2;                        // < 3*G2*Ff
    int mod = j / (G2 * Ff), r = j - mod * (G2 * Ff);
    int n = r >> 7, k = r & 127;             // W[n][k], n<256, k<128
    int t = n >> 4, nl = n & 15;             // n-tile, n-in-tile
    int c = k >> 5, q = (k >> 3) & 3, e = k & 7;  // k-chunk, quad, elem
    const float* W = (mod == 0) ? Wi : (mod == 1) ? Wq : Wvp;
    wbar[mod * G2 * Ff + (((t * 4 + c) * 64 + q * 16 + nl) * 8) + e] = f2bfs(W[r]);
  }
}

// ---------------- K1: AMLP f-GEMM + pooled p + sum(f^2) + fused x-transpose ---
// Transpose tail re-reads this block's 256x128 x tile (L1/L2-hot from the
// GEMM) and writes xT, eliminating the standalone transpose's 100MB cold HBM
// read (R6: net ~-20us). amlp mod {0,1,2}={txt,aud,vis} -> xT slot {2,0,1}.
__global__ void __launch_bounds__(256, 3) k_amlp(
    const float* __restrict__ txt, const float* __restrict__ aud, const float* __restrict__ vis,
    const float* __restrict__ bi, const float* __restrict__ bq, const float* __restrict__ bvp,
    const short* __restrict__ wbar,
    short* __restrict__ p1, short* __restrict__ p2, float* __restrict__ sumsq,
    short* __restrict__ xT) {
  int mod = blockIdx.y;
  const float* x    = (mod == 0) ? txt : (mod == 1) ? aud : vis;
  const float* bias = (mod == 0) ? bi  : (mod == 1) ? bq  : bvp;
  const short* wbm  = wbar + mod * G2 * Ff;
  short* pout = (mod == 0) ? p1 : (mod == 1) ? p2 : nullptr;

  __shared__ float wred[4];
  __shared__ float ttile[64][65];
  int tid = threadIdx.x, lane = tid & 63, wave = tid >> 6;
  int quad = lane >> 4, nl = lane & 15;

  bfrag wreg[4][4];
#pragma unroll
  for (int tt = 0; tt < 4; ++tt)
#pragma unroll
    for (int c = 0; c < 4; ++c)
      wreg[tt][c] = *(const bfrag*)(wbm + ((((wave * 4 + tt) * 4 + c) * 64 + lane) * 8));

  float bia[4];
#pragma unroll
  for (int tt = 0; tt < 4; ++tt) bia[tt] = bias[wave * 64 + tt * 16 + nl];

  const float* xblk = x + (size_t)(blockIdx.x * 256) * Ff;
  facc zero = {0.f, 0.f, 0.f, 0.f};
  float sq = 0.f;

  float4 buf[8];
  {
    const float* xrow = xblk + (size_t)nl * Ff;
#pragma unroll
    for (int c = 0; c < 4; ++c) {
      buf[c * 2]     = *(const float4*)(xrow + c * 32 + quad * 8);
      buf[c * 2 + 1] = *(const float4*)(xrow + c * 32 + quad * 8 + 4);
    }
  }

  for (int g = 0; g < 16; ++g) {
    bfrag af[4];
#pragma unroll
    for (int c = 0; c < 4; ++c) {
      float4 a0 = buf[c * 2], a1 = buf[c * 2 + 1];
      af[c][0] = (__bf16)a0.x; af[c][1] = (__bf16)a0.y;
      af[c][2] = (__bf16)a0.z; af[c][3] = (__bf16)a0.w;
      af[c][4] = (__bf16)a1.x; af[c][5] = (__bf16)a1.y;
      af[c][6] = (__bf16)a1.z; af[c][7] = (__bf16)a1.w;
    }
    if (g < 15) {
      const float* xrow = xblk + (size_t)((g + 1) * 16 + nl) * Ff;
#pragma unroll
      for (int c = 0; c < 4; ++c) {
        buf[c * 2]     = *(const float4*)(xrow + c * 32 + quad * 8);
        buf[c * 2 + 1] = *(const float4*)(xrow + c * 32 + quad * 8 + 4);
      }
    }
    facc acc[4];
#pragma unroll
    for (int tt = 0; tt < 4; ++tt) acc[tt] = zero;
#pragma unroll
    for (int c = 0; c < 4; ++c)
#pragma unroll
      for (int tt = 0; tt < 4; ++tt)
        acc[tt] = mfma16(af[c], wreg[tt][c], acc[tt]);

    int drow = blockIdx.x * 256 + g * 16 + quad * 4;
#pragma unroll
    for (int tt = 0; tt < 4; ++tt)
#pragma unroll
      for (int r = 0; r < 4; ++r) {
        float fv = acc[tt][r] + bia[tt];
        sq += fv * fv;
        if (pout) {
          float fo = fv + __shfl_xor(fv, 1, 64);       // pair-pool along n
          if ((lane & 1) == 0)
            pout[(size_t)(drow + r) * Ff + wave * 32 + tt * 8 + (nl >> 1)] = f2bfs(fo);
        }
      }
  }
  for (int off = 32; off > 0; off >>= 1) sq += __shfl_down(sq, off, 64);
  if (lane == 0) wred[wave] = sq;
  __syncthreads();
  if (tid == 0) atomicAdd(&sumsq[mod], wred[0] + wred[1] + wred[2] + wred[3]);

  // ---- fused transpose tail: 8 sub-tiles of 64s x 64f ----
  int slot = (mod == 0) ? 2 : (mod == 1) ? 0 : 1;
  int b = blockIdx.x >> 2, s0 = (blockIdx.x & 3) * 256;
  short* xdst = xT + ((size_t)slot * Bb + b) * Ff * Ss;
  for (int t = 0; t < 8; ++t) {
    int sc = (t >> 1) * 64, fc = (t & 1) * 64;
    __syncthreads();
    {
      int fg = tid & 15, sb = tid >> 4;
#pragma unroll
      for (int i = 0; i < 4; ++i) {
        int si = i * 16 + sb;
        float4 v = *(const float4*)(x + ((size_t)b * Ss + s0 + sc + si) * Ff + fc + fg * 4);
        ttile[si][fg * 4 + 0] = v.x;
        ttile[si][fg * 4 + 1] = v.y;
        ttile[si][fg * 4 + 2] = v.z;
        ttile[si][fg * 4 + 3] = v.w;
      }
    }
    __syncthreads();
    {
      int sg = tid & 15, fb = tid >> 4;
#pragma unroll
      for (int i = 0; i < 4; ++i) {
        int fi = i * 16 + fb;
        s4v v;
        v[0] = f2bfs(ttile[sg * 4 + 0][fi]);
        v[1] = f2bfs(ttile[sg * 4 + 1][fi]);
        v[2] = f2bfs(ttile[sg * 4 + 2][fi]);
        v[3] = f2bfs(ttile[sg * 4 + 3][fi]);
        *(s4v*)(xdst + (size_t)(fc + fi) * Ss + s0 + sc + sg * 4) = v;
      }
    }
  }
}

// ---------------- K2: column norms over s of z, vectorized s8v loads ----------
__global__ void k_colnorm(const short* __restrict__ p1, const short* __restrict__ p2,
                          const float* __restrict__ sumsq, float* __restrict__ colnsq) {
  __shared__ float part[16][128];
  float n1 = sqrtf(sumsq[0]), n2 = sqrtf(sumsq[1]), n3 = sqrtf(sumsq[2]);
  float w1 = n1 / (n1 + n2), w2 = n2 / (n1 + n2);
  float tc = 2.f * n3 * n3 / (n1 + n2 + n3);
  int b = blockIdx.x, s0 = blockIdx.y * 128;
  int tid = threadIdx.x, fi = (tid & 15) * 8, sl = tid >> 4;
  float a[8];
#pragma unroll
  for (int j = 0; j < 8; ++j) a[j] = 0.f;
  for (int st = 0; st < 8; ++st) {
    size_t off = ((size_t)b * Ss + s0 + st * 16 + sl) * Ff + fi;
    s8v v1 = *(const s8v*)(p1 + off);
    s8v v2 = *(const s8v*)(p2 + off);
#pragma unroll
    for (int j = 0; j < 8; ++j) {
      float z = w1 * bf2fs(v1[j]) + w2 * bf2fs(v2[j]) + tc;
      a[j] += z * z;
    }
  }
#pragma unroll
  for (int j = 0; j < 8; ++j) part[sl][fi + j] = a[j];
  __syncthreads();
  if (tid < 128) {
    float s = 0.f;
    for (int i = 0; i < 16; ++i) s += part[i][tid];
    atomicAdd(&colnsq[b * Ff + tid], s);
  }
}

// ---------------- K3: gT[b][f][s] = z * invcn, tiled transpose ----------------
__global__ void k_gnormT(const short* __restrict__ p1, const short* __restrict__ p2,
                         const float* __restrict__ sumsq, const float* __restrict__ colnsq,
                         short* __restrict__ gT) {
  __shared__ float tile[64][65];
  __shared__ float invcn[64];
  float n1 = sqrtf(sumsq[0]), n2 = sqrtf(sumsq[1]), n3 = sqrtf(sumsq[2]);
  float w1 = n1 / (n1 + n2), w2 = n2 / (n1 + n2);
  float tc = 2.f * n3 * n3 / (n1 + n2 + n3);
  int b = blockIdx.z, s0 = blockIdx.x * 64, f0 = blockIdx.y * 64;
  int tid = threadIdx.x;
  if (tid < 64)
    invcn[tid] = 1.f / fmaxf(sqrtf(colnsq[b * Ff + f0 + tid]), 1e-12f);
  __syncthreads();
  for (int i = 0; i < 16; ++i) {
    int idx = i * 256 + tid;
    int si = idx >> 6, fi = idx & 63;
    size_t off = ((size_t)b * Ss + s0 + si) * Ff + f0 + fi;
    float z = w1 * bf2fs(p1[off]) + w2 * bf2fs(p2[off]) + tc;
    tile[si][fi] = z * invcn[fi];
  }
  __syncthreads();
  short* dst = gT + (size_t)b * Ff * Ss;
  {
    int sg = tid & 15, fb = tid >> 4;
#pragma unroll
    for (int i = 0; i < 4; ++i) {
      int fi = i * 16 + fb;
      s4v v;
      v[0] = f2bfs(tile[sg * 4 + 0][fi]);
      v[1] = f2bfs(tile[sg * 4 + 1][fi]);
      v[2] = f2bfs(tile[sg * 4 + 2][fi]);
      v[3] = f2bfs(tile[sg * 4 + 3][fi]);
      *(s4v*)(dst + (size_t)(f0 + fi) * Ss + s0 + sg * 4) = v;
    }
  }
}

// ---------------- K4: M-GEMM (N=1152 incl. T2 cols), XOR-swizzled LDS --------
// Single-buffered 2-phase loop (proven best). XCD swizzle on M.
__global__ void __launch_bounds__(256) k_mgemm(const short* __restrict__ xT,
                                               const short* __restrict__ aextT,
                                               short* __restrict__ mxext) {
  int mod = blockIdx.z;
  const short* Ap = xT + (size_t)mod * Bb * Ff * Ss;
  const short* Bp = aextT + (size_t)mod * NE * Ss;
  short* Op = mxext + (size_t)mod * Bb * Ff * NE;
  int bx = blockIdx.x;
  int swzx = (bx & 7) * 8 + (bx >> 3);       // bijective on 64
  int M0 = swzx * 128, N0 = blockIdx.y * 128;
  __shared__ short As[128 * 64];   // 16KB
  __shared__ short Bs[128 * 64];   // 16KB
  int tid = threadIdx.x, lane = tid & 63, wave = tid >> 6;
  int quad = lane >> 4, nl = lane & 15;
  int wm = (wave >> 1) * 64, wn = (wave & 1) * 64;
  facc zero = {0.f, 0.f, 0.f, 0.f};
  facc acc[4][4];
  for (int i = 0; i < 4; ++i) for (int j = 0; j < 4; ++j) acc[i][j] = zero;
  for (int k0 = 0; k0 < Ss; k0 += 64) {
    __syncthreads();
#pragma unroll
    for (int i = 0; i < 4; ++i) {
      int idx = i * 256 + tid;
      int r = idx >> 3, cs = ((idx & 7) ^ (r & 7)) * 8;
      gld16(Ap + (size_t)(M0 + r) * Ss + k0 + cs, As + idx * 8);
      gld16(Bp + (size_t)(N0 + r) * Ss + k0 + cs, Bs + idx * 8);
    }
    __syncthreads();
#pragma unroll
    for (int kc = 0; kc < 2; ++kc) {
      bfrag a[4], bfr[4];
      for (int mt = 0; mt < 4; ++mt) {
        int row = wm + mt * 16 + nl;
        a[mt] = *(const bfrag*)(As + row * 64 + (((kc * 4 + quad) ^ (row & 7)) * 8));
      }
      for (int nt = 0; nt < 4; ++nt) {
        int row = wn + nt * 16 + nl;
        bfr[nt] = *(const bfrag*)(Bs + row * 64 + (((kc * 4 + quad) ^ (row & 7)) * 8));
      }
      for (int mt = 0; mt < 4; ++mt)
        for (int nt = 0; nt < 4; ++nt)
          acc[mt][nt] = mfma16(a[mt], bfr[nt], acc[mt][nt]);
    }
  }
  for (int mt = 0; mt < 4; ++mt)
    for (int nt = 0; nt < 4; ++nt)
      for (int r = 0; r < 4; ++r) {
        int row = M0 + wm + mt * 16 + quad * 4 + r;
        int col = N0 + wn + nt * 16 + nl;
        Op[(size_t)row * NE + col] = f2bfs(acc[mt][nt][r]);
      }
}

// ---------------- K5: fused C-GEMM + H-GEMM, M-split (R5-proven form) ---------
// grid (B, 3, 2): block computes 64 C-rows (64x256 tile) + 64 H-rows. T2 bias
// read from mx columns [Ss, Ss+Kk) in the epilogue. R6's mod-pairing variant
// regressed hard (acc[2][..] scratch spill, rule #20) -- do not re-introduce.
__global__ void __launch_bounds__(256) k_chgemm(const short* __restrict__ mxext,
                                                const short* __restrict__ xT,
                                                const short* __restrict__ gT,
                                                const short* __restrict__ wcb,
                                                short* __restrict__ h) {
  int b = blockIdx.x, mod = blockIdx.y, half = blockIdx.z;
  int r0 = half * 64;                        // this block's C-row offset
  const short* Ap = mxext + ((size_t)mod * Bb + b) * Ff * NE;
  // a,v use aud (xT slot 0, source bug); t uses txt (slot 2)
  const short* xTb = xT + (size_t)((mod == 2) ? 2 : 0) * Bb * Ff * Ss + (size_t)b * Ff * Ss;
  const short* gTb = gT + (size_t)b * Ff * Ss;
  const short* Wp = wcb + (size_t)mod * Kk * G2;
  short* Hp = h + ((size_t)mod * Bb + b) * Ff * Kk;

  __shared__ short smem[64 * 64 + 256 * 64];   // 40KB
  short* As = smem;                            // [64][64] staging
  short* Bs = smem + 64 * 64;                  // [256][64] staging
  // Cs = smem reused as [64][280] after staging is dead (35KB < 40KB)

  int tid = threadIdx.x, lane = tid & 63, wave = tid >> 6;
  int quad = lane >> 4, nl = lane & 15;
  int wn = wave * 64;                          // wave owns 64 cols, all 64 rows
  facc zero = {0.f, 0.f, 0.f, 0.f};
  facc acc[4][4];
  for (int i = 0; i < 4; ++i) for (int j = 0; j < 4; ++j) acc[i][j] = zero;
  for (int k0 = 0; k0 < Ss; k0 += 64) {
    __syncthreads();
#pragma unroll
    for (int i = 0; i < 2; ++i) {              // A: 64 rows
      int idx = i * 256 + tid;
      int r = idx >> 3, cs = ((idx & 7) ^ (r & 7)) * 8;
      gld16(Ap + (size_t)(r0 + r) * NE + k0 + cs, As + idx * 8);
    }
#pragma unroll
    for (int i = 0; i < 8; ++i) {              // B: 256 rows (128 x | 128 g)
      int idx = i * 256 + tid;
      int r = idx >> 3, cs = ((idx & 7) ^ (r & 7)) * 8;
      const short* src = (r < 128) ? (xTb + (size_t)r * Ss) : (gTb + (size_t)(r - 128) * Ss);
      gld16(src + k0 + cs, Bs + idx * 8);
    }
    __syncthreads();
#pragma unroll
    for (int kc = 0; kc < 2; ++kc) {
      bfrag a[4], bfr[4];
      for (int mt = 0; mt < 4; ++mt) {
        int row = mt * 16 + nl;
        a[mt] = *(const bfrag*)(As + row * 64 + (((kc * 4 + quad) ^ (row & 7)) * 8));
      }
      for (int nt = 0; nt < 4; ++nt) {
        int row = wn + nt * 16 + nl;
        bfr[nt] = *(const bfrag*)(Bs + row * 64 + (((kc * 4 + quad) ^ (row & 7)) * 8));
      }
      for (int mt = 0; mt < 4; ++mt)
        for (int nt = 0; nt < 4; ++nt)
          acc[mt][nt] = mfma16(a[mt], bfr[nt], acc[mt][nt]);
    }
  }
  __syncthreads();                            // staging dead; reuse smem as Cs
  short* Cs = smem;
  for (int mt = 0; mt < 4; ++mt)
    for (int nt = 0; nt < 4; ++nt)
      for (int r = 0; r < 4; ++r) {
        int row = mt * 16 + quad * 4 + r;     // local C row (0..63)
        int col = wn + nt * 16 + nl;
        Cs[row * 280 + col] = f2bfs(tanhf(acc[mt][nt][r] * 0.0625f));
      }
  __syncthreads();
  // H phase: wave w handles local C rows [16w, 16w+16)
  facc hacc[4];
  for (int nt = 0; nt < 4; ++nt) hacc[nt] = zero;
  for (int k0 = 0; k0 < G2; k0 += 32) {
    bfrag ca = *(const bfrag*)(Cs + (wave * 16 + nl) * 280 + k0 + quad * 8);
    for (int nt = 0; nt < 4; ++nt) {
      bfrag wb = *(const bfrag*)(Wp + (size_t)(nt * 16 + nl) * G2 + k0 + quad * 8);
      hacc[nt] = mfma16(ca, wb, hacc[nt]);
    }
  }
  for (int nt = 0; nt < 4; ++nt)
    for (int r = 0; r < 4; ++r) {
      int lrow = wave * 16 + quad * 4 + r;       // local row
      int col = nt * 16 + nl;
      float v = hacc[nt][r] + bf2fs(Ap[(size_t)(r0 + lrow) * NE + Ss + col]);  // + T2
      Hp[(size_t)(r0 + lrow) * Kk + col] = f2bfs(fmaxf(v, 0.f));
    }
}

// ---------------- K7: out = Wh @ H^T + residual ------------------------------
__global__ void k_outgemm(const short* __restrict__ whb, const short* __restrict__ h,
                          const float* __restrict__ txt, const float* __restrict__ aud,
                          const float* __restrict__ vis, float* __restrict__ outp) {
  int s0 = blockIdx.x * 128, b = blockIdx.y, mod = blockIdx.z;
  const short* Wp = whb + (size_t)mod * Ss * Kk;
  const short* Hp = h + ((size_t)mod * Bb + b) * Ff * Kk;
  const float* xres = ((mod == 0) ? aud : (mod == 1) ? vis : txt) + (size_t)b * Ss * Ff;
  int slot = (mod == 0) ? 1 : (mod == 1) ? 2 : 0;   // output order (t, a, v)
  float* Op = outp + ((size_t)slot * Bb + b) * Ss * Ff;
  int tid = threadIdx.x, lane = tid & 63, wave = tid >> 6;
  int quad = lane >> 4, nl = lane & 15;
  int wm = (wave >> 1) * 64, wn = (wave & 1) * 64;
  facc zero = {0.f, 0.f, 0.f, 0.f};
  facc acc[4][4];
  for (int i = 0; i < 4; ++i) for (int j = 0; j < 4; ++j) acc[i][j] = zero;
  for (int k0 = 0; k0 < Kk; k0 += 32) {
    bfrag a[4], bfr[4];
    for (int mt = 0; mt < 4; ++mt)
      a[mt] = *(const bfrag*)(Wp + (size_t)(s0 + wm + mt * 16 + nl) * Kk + k0 + quad * 8);
    for (int nt = 0; nt < 4; ++nt)
      bfr[nt] = *(const bfrag*)(Hp + (size_t)(wn + nt * 16 + nl) * Kk + k0 + quad * 8);
    for (int mt = 0; mt < 4; ++mt)
      for (int nt = 0; nt < 4; ++nt)
        acc[mt][nt] = mfma16(a[mt], bfr[nt], acc[mt][nt]);
  }
  for (int mt = 0; mt < 4; ++mt)
    for (int nt = 0; nt < 4; ++nt)
      for (int r = 0; r < 4; ++r) {
        int srow = s0 + wm + mt * 16 + quad * 4 + r;
        int col = wn + nt * 16 + nl;
        size_t o = (size_t)srow * Ff + col;
        Op[o] = acc[mt][nt][r] + xres[o];
      }
}

extern "C" void kernel_launch(void* const* d_in, const int* in_sizes, int n_in,
                              void* d_out, int out_size, void* d_ws, size_t ws_size,
                              hipStream_t stream) {
  const float* txt = (const float*)d_in[0];
  const float* aud = (const float*)d_in[1];
  const float* vis = (const float*)d_in[2];
  const float* Wi  = (const float*)d_in[3];
  const float* bi  = (const float*)d_in[4];
  const float* Wq  = (const float*)d_in[5];
  const float* bq  = (const float*)d_in[6];
  const float* Wvp = (const float*)d_in[7];
  const float* bvp = (const float*)d_in[8];
  const float* Aa  = (const float*)d_in[9];
  const float* Av  = (const float*)d_in[10];
  const float* Al  = (const float*)d_in[11];
  const float* Wa  = (const float*)d_in[12];
  const float* Wv  = (const float*)d_in[13];
  const float* Wt  = (const float*)d_in[14];
  const float* Wca = (const float*)d_in[15];
  const float* Wcv = (const float*)d_in[16];
  const float* Wct = (const float*)d_in[17];
  const float* Wha = (const float*)d_in[18];
  const float* Whv = (const float*)d_in[19];
  const float* Wht = (const float*)d_in[20];

  char* w = (char*)d_ws;
  float* sumsq  = (float*)w;                    // 3 floats
  float* colnsq = (float*)(w + 256);            // B*F floats
  size_t off = 65536;
  short* xT    = (short*)(w + off); off += (size_t)3 * Bb * Ff * Ss * 2;   // 48MB
  short* aextT = (short*)(w + off); off += (size_t)3 * NE * Ss * 2;        // 6.75MB
  short* gT    = (short*)(w + off); off += (size_t)Bb * Ff * Ss * 2;       // 16MB
  short* mx    = (short*)(w + off);                                        // 54MB
  short* p1    = mx;                             // p1/p2 overlaid under mx:
  short* p2    = mx + (size_t)Bb * Ss * Ff;      // dead before k_mgemm writes
  off += (size_t)3 * Bb * Ff * NE * 2;
  short* h     = (short*)(w + off); off += (size_t)3 * Bb * Ff * Kk * 2;   // 3MB
  short* wcb   = (short*)(w + off); off += (size_t)3 * Kk * G2 * 2;
  short* whb   = (short*)(w + off); off += (size_t)3 * Ss * Kk * 2;
  short* wbar  = (short*)(w + off); off += (size_t)3 * G2 * Ff * 2;

  hipMemsetAsync(d_ws, 0, 65536, stream);   // zero sumsq + colnsq
  k_build_aextT<<<dim3(NE / 64, 16, 3), 256, 0, stream>>>(Aa, Av, Al, Wa, Wv, Wt, aextT);
  k_build_w<<<(3 * Kk * G2 + 3 * Ss * Kk + 3 * G2 * Ff) / 256, 256, 0, stream>>>(
      Wca, Wcv, Wct, Wha, Whv, Wht, Wi, Wq, Wvp, wcb, whb, wbar);
  k_amlp<<<dim3(Bb * Ss / 256, 3), 256, 0, stream>>>(txt, aud, vis, bi, bq, bvp,
                                                     wbar, p1, p2, sumsq, xT);
  k_colnorm<<<dim3(Bb, 8), 256, 0, stream>>>(p1, p2, sumsq, colnsq);
  k_gnormT<<<dim3(16, 2, Bb), 256, 0, stream>>>(p1, p2, sumsq, colnsq, gT);
  k_mgemm<<<dim3(Bb * Ff / 128, NE / 128, 3), 256, 0, stream>>>(xT, aextT, mx);
  k_chgemm<<<dim3(Bb, 3, 2), 256, 0, stream>>>(mx, xT, gT, wcb, h);
  k_outgemm<<<dim3(Ss / 128, Bb, 3), 256, 0, stream>>>(whb, h, txt, aud, vis, (float*)d_out);
}